// Round 10
// baseline (7432.672 us; speedup 1.0000x reference)
//
#include <hip/hip_runtime.h>
#include <hip/hip_bf16.h>
#include <math.h>

typedef __attribute__((ext_vector_type(4))) float vf4;
typedef __attribute__((ext_vector_type(8))) short vbf8;
typedef __attribute__((ext_vector_type(8))) unsigned short vus8;

#define NWG   128
#define NTHR  256
#define LEN   1024
#define H3    3072
#define CND   80
#define EMBD  128

// ---- ws byte offsets ----
#define TAB1_B  0ull
#define TAB2_B  (TAB1_B + 786432ull*4)
#define TAB3_B  (TAB2_B + 786432ull*4)
#define BF_B    (TAB3_B + 786432ull*4)            // bfrag: 128oct*2which*35frag*512 bf16
#define MELA_B  (BF_B   + 4587520ull*2)           // melA : 1024t*2m*3frag*512 bf16
#define AF_B    (MELA_B + 3145728ull*2)           // Afrag: 1025t*64frag*512 bf16
#define CNT_B   (AF_B   + 33587200ull*2)          // 8 counters, 256B apart
#define FOFS    8388608ull                        // flogits offset in d_out

// ============================ prep kernels (unchanged) ============================

__global__ __launch_bounds__(256) void make_tables(const float* __restrict__ IW,
                                                   const float* __restrict__ Ib,
                                                   const float* __restrict__ cemb,
                                                   const float* __restrict__ femb,
                                                   float* __restrict__ tab1,
                                                   float* __restrict__ tab2,
                                                   float* __restrict__ tab3) {
    int blk = blockIdx.x;
    int table = blk / 3072;
    int rem = blk % 3072;
    int row = rem / 12;
    int cc = rem % 12;
    int col = cc * 256 + threadIdx.x;
    int ofs = CND + table * EMBD;
    const float* emb = (table == 1) ? femb : cemb;
    float acc = 0.f;
    for (int k = 0; k < EMBD; ++k)
        acc += emb[row * EMBD + k] * IW[(size_t)(ofs + k) * H3 + col];
    if (table == 0) acc += Ib[col];
    if (table == 2 && ((col & 1023) < 768)) acc = 0.f;
    float* dst = (table == 0) ? tab1 : (table == 1 ? tab2 : tab3);
    dst[(size_t)row * H3 + col] = acc;
}

// B frag layout: [octet 0..127][which 0..1][kk 0..34][lane 0..63][elem 0..7]
__global__ __launch_bounds__(256) void build_bfrag(const float* __restrict__ Rw,
                                                   const float* __restrict__ IW,
                                                   const float* __restrict__ Rb,
                                                   unsigned short* __restrict__ Bf) {
    long idx = (long)blockIdx.x * 256 + threadIdx.x;
    int elem = idx & 7;
    int lane = (idx >> 3) & 63;
    int kk   = (int)((idx >> 9) % 35);
    int n    = (int)((idx / (512 * 35)) & 1);
    int oc   = (int)(idx / (512 * 35 * 2));
    int c    = lane & 15;
    int k    = kk * 32 + ((lane >> 4) & 3) * 8 + elem;
    int jj   = oc * 8 + (c & 7);
    float v = 0.f;
    if (n == 0) {
        int col = (c >> 3) * 1024 + jj;
        if (k < 1024)       v = Rw[(size_t)k * H3 + col];
        else if (k < 1104)  v = IW[(size_t)(k - 1024) * H3 + col];
        else if (k == 1104) v = Rb[col];
    } else {
        if ((c >> 3) == 0) {
            if (k < 1024)       v = Rw[(size_t)k * H3 + 2048 + jj];
            else if (k == 1104) v = Rb[2048 + jj];
        } else {
            if (k >= 1024 && k < 1104) v = IW[(size_t)(k - 1024) * H3 + 2048 + jj];
        }
    }
    __hip_bfloat16 hb = __float2bfloat16(v);
    Bf[idx] = *(unsigned short*)&hb;
}

__global__ __launch_bounds__(256) void build_melA(const float* __restrict__ mel,
                                                  unsigned short* __restrict__ MelA) {
    long idx = (long)blockIdx.x * 256 + threadIdx.x;
    int elem = idx & 7;
    int lane = (idx >> 3) & 63;
    int kkm  = (int)((idx >> 9) % 3);
    int m    = (int)((idx / 1536) & 1);
    int t    = (int)(idx / 3072);
    int b    = m * 16 + (lane & 15);
    int km   = kkm * 32 + ((lane >> 4) & 3) * 8 + elem;
    float v = (km < CND) ? mel[((size_t)b * LEN + t) * CND + km] : (km == CND ? 1.f : 0.f);
    __hip_bfloat16 hb = __float2bfloat16(v);
    MelA[idx] = *(unsigned short*)&hb;
}

// ============================ persistent scan ============================
// 128 WGs x 256 thr (4 waves, 2m x 2n). Composition of measured-best pieces:
//  - B (70KB) resident in LDS (r9: correct + kills per-step B refetch; immune
//    to the acquire-fence invalidate).
//  - A = h[t]: per-wave plain cached loads interleaved with the MFMA loop
//    (r4: compiler overlaps load latency with MFMA issue -- beats r9's
//    serialized PULL stage even at 2x intra-WG duplication).
//  - Barrier: r4's measured-best (8 spread RMW counters, RELEASE add; 8-lane
//    relaxed poll + ballot; ONE agent-acquire fence). Phase-A (x-idx, table
//    gathers, mel MFMA from LDS-B) overlaps the wait.
__global__ __launch_bounds__(256, 1) void scan_persist(const unsigned short* __restrict__ Bf,
                                                       const unsigned short* __restrict__ MelA,
                                                       unsigned short* __restrict__ Af,
                                                       const float* __restrict__ tab1,
                                                       const float* __restrict__ tab2,
                                                       const float* __restrict__ tab3,
                                                       const int* __restrict__ xin,
                                                       unsigned int* __restrict__ cnt) {
    __shared__ __align__(16) unsigned short Bs[2 * 35 * 512];   // 71,680 B
    __shared__ float ex[32][36];                                //  4,608 B

    int tid = threadIdx.x;
    int wg  = blockIdx.x;
    int lane = tid & 63;
    int wv = tid >> 6;            // 0..3
    int m  = wv >> 1;             // A half (batch 0-15 / 16-31)
    int n  = wv & 1;              // 0: [u|r] cols, 1: [e1|e2] cols

    // ---- stage this WG's B fragments into LDS (one-time) ----
    {
        const unsigned int* src = (const unsigned int*)(Bf + (size_t)wg * (2 * 35 * 512));
        unsigned int* dst = (unsigned int*)Bs;
#pragma unroll
        for (int i = 0; i < 70; ++i) dst[tid + i * 256] = src[tid + i * 256];
    }
    __syncthreads();   // Bs complete before ANY read (incl. PHASE_A(0))

    // gate role: one (b, j) per thread
    int gb = tid >> 3, gjl = tid & 7;
    int gj = wg * 8 + gjl;
    float hreg = 0.f;
    size_t wbase = (size_t)(((gb >> 4) * 32 + (gj >> 5)) * 512 +
                            ((gb & 15) + 16 * ((gj >> 3) & 3)) * 8 + (gj & 7));

    // phase-A carried state
    float tsu = 0.f, tsr = 0.f, tse = 0.f;
    vf4 amel = {0.f, 0.f, 0.f, 0.f};

    const unsigned short* Bn = Bs + (n * 35) * 512 + lane * 8;

#define PHASE_A(tt) do {                                                          \
        int ci = xin[(gb * LEN + (tt)) * 2];                                      \
        int fi = xin[(gb * LEN + (tt)) * 2 + 1];                                  \
        int cn = xin[(gb * LEN + (((tt) + 1) & (LEN - 1))) * 2];                  \
        const float* p1 = tab1 + (size_t)ci * H3 + gj;                            \
        const float* p2 = tab2 + (size_t)fi * H3 + gj;                            \
        const float* p3 = tab3 + (size_t)cn * H3 + gj;                            \
        float a1u = p1[0],    a2u = p2[0],    a3u = p3[0];                        \
        float a1r = p1[1024], a2r = p2[1024], a3r = p3[1024];                     \
        float a1e = p1[2048], a2e = p2[2048], a3e = p3[2048];                     \
        tsu = a1u + a2u + a3u;                                                    \
        tsr = a1r + a2r + a3r;                                                    \
        tse = a1e + a2e + a3e;                                                    \
        const unsigned short* Am = MelA + (size_t)(tt) * 3072 +                   \
                                   (size_t)(m * 3) * 512 + lane * 8;              \
        vf4 am = {0.f, 0.f, 0.f, 0.f};                                            \
        _Pragma("unroll")                                                         \
        for (int kq = 0; kq < 3; ++kq) {                                          \
            vbf8 a = *(const vbf8*)(Am + kq * 512);                               \
            vbf8 b = *(const vbf8*)(Bn + (32 + kq) * 512);                        \
            am = __builtin_amdgcn_mfma_f32_16x16x32_bf16(a, b, am, 0, 0, 0);      \
        }                                                                         \
        amel = am;                                                                \
    } while (0)

    PHASE_A(0);

#pragma unroll 1
    for (int t = 0; t < LEN; ++t) {
        // ---- D(16x16) = h(16x1024) x B + carried mel/bias part ----
        // A: plain cached global loads (post-fence = fresh), interleaved with
        // MFMA by the compiler; B: LDS.
        const unsigned short* Ah = Af + (size_t)t * 32768 + (size_t)(m * 32) * 512 + lane * 8;
        vf4 acc0 = amel, acc1 = {0.f, 0.f, 0.f, 0.f};
#pragma unroll
        for (int kk = 0; kk < 32; kk += 2) {
            vbf8 a0 = *(const vbf8*)(Ah + kk * 512);
            vbf8 b0 = *(const vbf8*)(Bn + kk * 512);
            acc0 = __builtin_amdgcn_mfma_f32_16x16x32_bf16(a0, b0, acc0, 0, 0, 0);
            vbf8 a1 = *(const vbf8*)(Ah + (kk + 1) * 512);
            vbf8 b1 = *(const vbf8*)(Bn + (kk + 1) * 512);
            acc1 = __builtin_amdgcn_mfma_f32_16x16x32_bf16(a1, b1, acc1, 0, 0, 0);
        }
        vf4 acc = acc0 + acc1;

        // ---- exchange pre-activations (C: col=lane&15, row=(lane>>4)*4+r) ----
#pragma unroll
        for (int r = 0; r < 4; ++r)
            ex[m * 16 + ((lane >> 4) * 4 + r)][n * 16 + (lane & 15)] = acc[r];
        __syncthreads();

        // ---- gates + state update ----
        float gu  = ex[gb][gjl]      + tsu;
        float gr  = ex[gb][8 + gjl]  + tsr;
        float e1  = ex[gb][16 + gjl];
        float ge2 = ex[gb][24 + gjl] + tse;
        float u  = 1.f / (1.f + expf(-gu));
        float r_ = 1.f / (1.f + expf(-gr));
        float e  = tanhf(r_ * e1 + ge2);
        hreg = u * hreg + (1.f - u) * e;

        // ---- coherent packed store of h (pair via shfl) ----
        __hip_bfloat16 hb = __float2bfloat16(hreg);
        int myv = (int)(*(unsigned short*)&hb);
        int nbv = __shfl_xor(myv, 1);
        if ((tid & 1) == 0) {
            unsigned int pk = ((unsigned)myv & 0xffffu) | ((unsigned)nbv << 16);
            __hip_atomic_store((unsigned int*)(Af + (size_t)(t + 1) * 32768 + wbase), pk,
                               __ATOMIC_RELAXED, __HIP_MEMORY_SCOPE_AGENT);
        }

        // ---- arrive: all h-stores drained (syncthreads => vmcnt0) ----
        __syncthreads();
        if (tid == 0)
            __hip_atomic_fetch_add(&cnt[(wg & 7) * 64], 1u,
                                   __ATOMIC_RELEASE, __HIP_MEMORY_SCOPE_AGENT);

        if (t + 1 < LEN) {
            // ---- phase A for t+1 (independent of h[t+1]) ----
            PHASE_A(t + 1);

            // ---- wait: wave 0, lanes 0..7 poll the 8 counters; ballot ----
            if (tid < 64) {
                unsigned tgt = (unsigned)(t + 1) * 16;   // 16 WGs per counter
                for (;;) {
                    unsigned v = tgt;
                    if (lane < 8)
                        v = __hip_atomic_load(&cnt[lane * 64], __ATOMIC_RELAXED,
                                              __HIP_MEMORY_SCOPE_AGENT);
                    if (__all((int)(v >= tgt))) break;
                    __builtin_amdgcn_s_sleep(1);
                }
                __builtin_amdgcn_fence(__ATOMIC_ACQUIRE, "agent");  // ONE L2 inv/step
            }
            __syncthreads();
            asm volatile("" ::: "memory");   // no load hoisting above the barrier
        }
    }
#undef PHASE_A
}

// ============================ output MLPs (unchanged) ============================
#define LOADF4(arr, ptr) { float4 _v = *(const float4*)(ptr); arr[0]=_v.x; arr[1]=_v.y; arr[2]=_v.z; arr[3]=_v.w; }

__device__ __forceinline__ void load_y8(const unsigned short* __restrict__ Af,
                                        int tslot, int b, int kk, float* o) {
    size_t off = (size_t)tslot * 32768 +
                 (size_t)(((b >> 4) * 32 + (kk >> 5)) * 512) +
                 (size_t)(((b & 15) + 16 * ((kk >> 3) & 3)) * 8);
    vus8 v = *(const vus8*)(Af + off);
#pragma unroll
    for (int e = 0; e < 8; ++e) o[e] = __uint_as_float(((unsigned)v[e]) << 16);
}

__global__ __launch_bounds__(256) void out_mlp(const unsigned short* __restrict__ Af,
                                               const float* __restrict__ O1w, const float* __restrict__ O1b,
                                               const float* __restrict__ O2w, const float* __restrict__ O2b,
                                               const float* __restrict__ O3w, const float* __restrict__ O3b,
                                               const float* __restrict__ O4w, const float* __restrict__ O4b,
                                               float* __restrict__ out) {
    __shared__ float z[16][768];
    int tid = threadIdx.x;
    int ig = tid >> 6;
    int lane = tid & 63;
    int R0 = blockIdx.x * 16;

    int rb[4], rt[4];
#pragma unroll
    for (int i = 0; i < 4; ++i) {
        int R = R0 + ig * 4 + i;
        rb[i] = R >> 10;
        rt[i] = (R & 1023) + 1;
    }

    for (int pass = 0; pass < 3; ++pass) {
        int c = pass * 256 + lane * 4;
        float acc[4][4];
#pragma unroll
        for (int i = 0; i < 4; ++i)
#pragma unroll
            for (int jj = 0; jj < 4; ++jj) acc[i][jj] = O1b[c + jj];
        for (int kk = 0; kk < 768; kk += 8) {
            float w[8][4];
#pragma unroll
            for (int dk = 0; dk < 8; ++dk) LOADF4(w[dk], &O1w[(size_t)(kk + dk) * 768 + c]);
            float ya[4][8];
#pragma unroll
            for (int i = 0; i < 4; ++i) load_y8(Af, rt[i], rb[i], kk, ya[i]);
#pragma unroll
            for (int i = 0; i < 4; ++i)
#pragma unroll
                for (int dk = 0; dk < 8; ++dk)
#pragma unroll
                    for (int jj = 0; jj < 4; ++jj)
                        acc[i][jj] += ya[i][dk] * w[dk][jj];
        }
#pragma unroll
        for (int i = 0; i < 4; ++i)
#pragma unroll
            for (int jj = 0; jj < 4; ++jj)
                z[ig * 4 + i][c + jj] = fmaxf(acc[i][jj], 0.f);
    }
    __syncthreads();

    {
        int c = lane * 4;
        float acc[4][4];
#pragma unroll
        for (int i = 0; i < 4; ++i)
#pragma unroll
            for (int jj = 0; jj < 4; ++jj) acc[i][jj] = O2b[c + jj];
        for (int kk = 0; kk < 768; kk += 4) {
            float w[4][4];
#pragma unroll
            for (int dk = 0; dk < 4; ++dk) LOADF4(w[dk], &O2w[(size_t)(kk + dk) * 256 + c]);
            float za[4][4];
#pragma unroll
            for (int i = 0; i < 4; ++i) LOADF4(za[i], &z[ig * 4 + i][kk]);
#pragma unroll
            for (int i = 0; i < 4; ++i)
#pragma unroll
                for (int dk = 0; dk < 4; ++dk)
#pragma unroll
                    for (int jj = 0; jj < 4; ++jj)
                        acc[i][jj] += za[i][dk] * w[dk][jj];
        }
#pragma unroll
        for (int i = 0; i < 4; ++i) {
            int R = R0 + ig * 4 + i;
#pragma unroll
            for (int jj = 0; jj < 4; ++jj)
                out[(size_t)R * 256 + c + jj] = acc[i][jj];
        }
    }
    __syncthreads();

    {
        int c = lane * 4;
        float acc[4][4];
#pragma unroll
        for (int i = 0; i < 4; ++i)
#pragma unroll
            for (int jj = 0; jj < 4; ++jj) acc[i][jj] = O3b[c + jj];
        for (int kk = 0; kk < 256; kk += 8) {
            float w[8][4];
#pragma unroll
            for (int dk = 0; dk < 8; ++dk) LOADF4(w[dk], &O3w[(size_t)(kk + dk) * 256 + c]);
            float ya[4][8];
#pragma unroll
            for (int i = 0; i < 4; ++i) load_y8(Af, rt[i], rb[i], 768 + kk, ya[i]);
#pragma unroll
            for (int i = 0; i < 4; ++i)
#pragma unroll
                for (int dk = 0; dk < 8; ++dk)
#pragma unroll
                    for (int jj = 0; jj < 4; ++jj)
                        acc[i][jj] += ya[i][dk] * w[dk][jj];
        }
        __syncthreads();
#pragma unroll
        for (int i = 0; i < 4; ++i)
#pragma unroll
            for (int jj = 0; jj < 4; ++jj)
                z[ig * 4 + i][c + jj] = fmaxf(acc[i][jj], 0.f);
    }
    __syncthreads();

    {
        int c = lane * 4;
        float acc[4][4];
#pragma unroll
        for (int i = 0; i < 4; ++i)
#pragma unroll
            for (int jj = 0; jj < 4; ++jj) acc[i][jj] = O4b[c + jj];
        for (int kk = 0; kk < 256; kk += 4) {
            float w[4][4];
#pragma unroll
            for (int dk = 0; dk < 4; ++dk) LOADF4(w[dk], &O4w[(size_t)(kk + dk) * 256 + c]);
            float za[4][4];
#pragma unroll
            for (int i = 0; i < 4; ++i) LOADF4(za[i], &z[ig * 4 + i][kk]);
#pragma unroll
            for (int i = 0; i < 4; ++i)
#pragma unroll
                for (int dk = 0; dk < 4; ++dk)
#pragma unroll
                    for (int jj = 0; jj < 4; ++jj)
                        acc[i][jj] += za[i][dk] * w[dk][jj];
        }
#pragma unroll
        for (int i = 0; i < 4; ++i) {
            int R = R0 + ig * 4 + i;
#pragma unroll
            for (int jj = 0; jj < 4; ++jj)
                out[FOFS + (size_t)R * 256 + c + jj] = acc[i][jj];
        }
    }
}

// ============================ launch ============================
extern "C" void kernel_launch(void* const* d_in, const int* in_sizes, int n_in,
                              void* d_out, int out_size, void* d_ws, size_t ws_size,
                              hipStream_t stream) {
    const int*   x    = (const int*)d_in[0];
    const float* mel  = (const float*)d_in[1];
    const float* Rw   = (const float*)d_in[2];
    const float* Rb   = (const float*)d_in[3];
    const float* IW   = (const float*)d_in[4];
    const float* Ib   = (const float*)d_in[5];
    const float* O1w  = (const float*)d_in[6];
    const float* O1b  = (const float*)d_in[7];
    const float* O2w  = (const float*)d_in[8];
    const float* O2b  = (const float*)d_in[9];
    const float* O3w  = (const float*)d_in[10];
    const float* O3b  = (const float*)d_in[11];
    const float* O4w  = (const float*)d_in[12];
    const float* O4b  = (const float*)d_in[13];
    const float* cemb = (const float*)d_in[14];
    const float* femb = (const float*)d_in[15];
    char* wsb = (char*)d_ws;
    float* out = (float*)d_out;

    float* tab1 = (float*)(wsb + TAB1_B);
    float* tab2 = (float*)(wsb + TAB2_B);
    float* tab3 = (float*)(wsb + TAB3_B);
    unsigned short* Bf   = (unsigned short*)(wsb + BF_B);
    unsigned short* MelA = (unsigned short*)(wsb + MELA_B);
    unsigned short* Af   = (unsigned short*)(wsb + AF_B);
    unsigned int*   cnt  = (unsigned int*)(wsb + CNT_B);

    make_tables<<<9216, 256, 0, stream>>>(IW, Ib, cemb, femb, tab1, tab2, tab3);
    build_bfrag<<<17920, 256, 0, stream>>>(Rw, IW, Rb, Bf);
    build_melA<<<12288, 256, 0, stream>>>(mel, MelA);
    hipMemsetAsync((void*)Af, 0, 65536, stream);   // h0 = 0
    hipMemsetAsync((void*)cnt, 0, 4096, stream);   // counters

    scan_persist<<<NWG, NTHR, 0, stream>>>(Bf, MelA, Af, tab1, tab2, tab3, x, cnt);

    out_mlp<<<2048, 256, 0, stream>>>(Af, O1w, O1b, O2w, O2b, O3w, O3b, O4w, O4b, out);
}

// Round 11
// 6241.570 us; speedup vs baseline: 1.1908x; 1.1908x over previous
//
#include <hip/hip_runtime.h>
#include <hip/hip_bf16.h>
#include <math.h>

typedef __attribute__((ext_vector_type(4))) float vf4;
typedef __attribute__((ext_vector_type(8))) short vbf8;
typedef __attribute__((ext_vector_type(8))) unsigned short vus8;

#define NWG   64
#define NTHR  512
#define LEN   1024
#define H3    3072
#define CND   80
#define EMBD  128

// ---- ws byte offsets ----
#define TAB1_B  0ull
#define TAB2_B  (TAB1_B + 786432ull*4)
#define TAB3_B  (TAB2_B + 786432ull*4)
#define BF_B    (TAB3_B + 786432ull*4)            // bfrag: 128oct*2which*35frag*512 bf16
#define MELA_B  (BF_B   + 4587520ull*2)           // melA : 1024t*2m*3frag*512 bf16
#define AF_B    (MELA_B + 3145728ull*2)           // Afrag: 1025t*64frag*512 bf16
#define CNT_B   (AF_B   + 33587200ull*2)          // 8 counters, 256B apart
#define FOFS    8388608ull                        // flogits offset in d_out

// ============================ prep kernels ============================

__global__ __launch_bounds__(256) void make_tables(const float* __restrict__ IW,
                                                   const float* __restrict__ Ib,
                                                   const float* __restrict__ cemb,
                                                   const float* __restrict__ femb,
                                                   float* __restrict__ tab1,
                                                   float* __restrict__ tab2,
                                                   float* __restrict__ tab3) {
    int blk = blockIdx.x;
    int table = blk / 3072;
    int rem = blk % 3072;
    int row = rem / 12;
    int cc = rem % 12;
    int col = cc * 256 + threadIdx.x;
    int ofs = CND + table * EMBD;
    const float* emb = (table == 1) ? femb : cemb;
    float acc = 0.f;
    for (int k = 0; k < EMBD; ++k)
        acc += emb[row * EMBD + k] * IW[(size_t)(ofs + k) * H3 + col];
    if (table == 0) acc += Ib[col];
    if (table == 2 && ((col & 1023) < 768)) acc = 0.f;
    float* dst = (table == 0) ? tab1 : (table == 1 ? tab2 : tab3);
    dst[(size_t)row * H3 + col] = acc;
}

// Coalesced B-frag builder: thread = (k, col); reads of Rw/IW are contiguous in
// col; scattered 2B stores into pre-zeroed Bf. Replaces the old builder whose
// reads strided 12KB per element (~16x line over-fetch).
// Frag layout unchanged: [oct][which][kk][lane][elem];
// which=0 cols [u x8 | r x8]; which=1 cols [e1 x8 | e2 x8].
__global__ __launch_bounds__(256) void build_bfrag2(const float* __restrict__ Rw,
                                                    const float* __restrict__ IW,
                                                    const float* __restrict__ Rb,
                                                    unsigned short* __restrict__ Bf) {
    int idx = blockIdx.x * 256 + threadIdx.x;     // k*3072 + col, k in 0..1119
    int col = idx % 3072;
    int k   = idx / 3072;
    float v;
    if (k < 1024)       v = Rw[(size_t)k * H3 + col];
    else if (k < 1104)  v = IW[(size_t)(k - 1024) * H3 + col];
    else if (k == 1104) v = Rb[col];
    else return;                                   // pad rows stay zero

    int g  = col >> 10;          // 0:u 1:r 2:e
    int j  = col & 1023;
    int oct = j >> 3, jo = j & 7;
    int which, c;
    if (g < 2)      { which = 0; c = g * 8 + jo; }
    else {
        which = 1;
        if (k < 1024 || k == 1104) c = jo;         // e1: h-part + Rb
        else                        c = 8 + jo;    // e2: mel rows
    }
    int kk = k >> 5, r5 = k & 31;
    int lane = (r5 >> 3) * 16 + c;
    int elem = r5 & 7;
    size_t dst = (((size_t)oct * 2 + which) * 35 + kk) * 512 + lane * 8 + elem;
    __hip_bfloat16 hb = __float2bfloat16(v);
    Bf[dst] = *(unsigned short*)&hb;
}

__global__ __launch_bounds__(256) void build_melA(const float* __restrict__ mel,
                                                  unsigned short* __restrict__ MelA) {
    long idx = (long)blockIdx.x * 256 + threadIdx.x;
    int elem = idx & 7;
    int lane = (idx >> 3) & 63;
    int kkm  = (int)((idx >> 9) % 3);
    int m    = (int)((idx / 1536) & 1);
    int t    = (int)(idx / 3072);
    int b    = m * 16 + (lane & 15);
    int km   = kkm * 32 + ((lane >> 4) & 3) * 8 + elem;
    float v = (km < CND) ? mel[((size_t)b * LEN + t) * CND + km] : (km == CND ? 1.f : 0.f);
    __hip_bfloat16 hb = __float2bfloat16(v);
    MelA[idx] = *(unsigned short*)&hb;
}

// ============================ persistent scan ============================
// r4's measured-best structure (64 WGs x 512 thr, 1 WG/CU) with exactly two
// diffs: (1) B resident in LDS (143KB, staged once) instead of the silent
// per-step L2 reload r4 paid (VGPR=116 proved Breg never stayed resident);
// (2) arrival spread over 8 RMW counters instead of 4. Everything else --
// inline tables, inline mel MFMAs, packed h store, tid0 poll + ONE
// agent-acquire fence (which also invalidates this CU's L1+L2 lines, keeping
// graph replays correct) -- is r4 verbatim.
__global__ __launch_bounds__(512, 2) void scan_persist(const unsigned short* __restrict__ Bf,
                                                       const unsigned short* __restrict__ MelA,
                                                       unsigned short* __restrict__ Af,
                                                       const float* __restrict__ tab1,
                                                       const float* __restrict__ tab2,
                                                       const float* __restrict__ tab3,
                                                       const int* __restrict__ xin,
                                                       unsigned int* __restrict__ cnt) {
    __shared__ __align__(16) unsigned short Bs[4 * 35 * 512];   // 143,360 B
    __shared__ float ex[32][68];                                //   8,704 B

    int tid = threadIdx.x;
    int wg  = blockIdx.x;
    int lane = tid & 63;
    int wv = tid >> 6;            // 0..7
    int m  = wv >> 2;             // A half (batch 0-15 / 16-31)
    int ng = wv & 3;              // B-set within WG: p=ng>>1 (octet), which=ng&1

    // ---- stage this WG's 4 B-sets into LDS (one-time; contiguous source) ----
    {
        const unsigned int* src = (const unsigned int*)(Bf + (size_t)wg * 4 * 35 * 512);
        unsigned int* dst = (unsigned int*)Bs;
#pragma unroll
        for (int i = 0; i < 70; ++i) dst[tid + i * 512] = src[tid + i * 512];
    }
    __syncthreads();   // Bs complete before ANY read

    // gate role
    int gb = tid >> 4, gjl = tid & 15;
    int gj = wg * 16 + gjl;
    float hreg = 0.f;
    size_t wbase = (size_t)(((gb >> 4) * 32 + (gj >> 5)) * 512 +
                            ((gb & 15) + 16 * ((gj >> 3) & 3)) * 8 + (gj & 7));

    const unsigned short* Bn = Bs + (size_t)ng * 35 * 512 + lane * 8;

#pragma unroll 1
    for (int t = 0; t < LEN; ++t) {
        // ---- A loads (plain cached; fresh post-fence) ----
        const unsigned short* Ah = Af + (size_t)t * 32768 + (size_t)(m * 32) * 512 + lane * 8;
        const unsigned short* Am = MelA + (size_t)t * 3072 + (size_t)(m * 3) * 512 + lane * 8;

        // ---- table gathers (issued early, consumed late) ----
        int ci = xin[(gb * LEN + t) * 2];
        int fi = xin[(gb * LEN + t) * 2 + 1];
        int cn = xin[(gb * LEN + ((t + 1) & (LEN - 1))) * 2];
        float t1u = tab1[(size_t)ci * H3 + gj];
        float t2u = tab2[(size_t)fi * H3 + gj];
        float t3u = tab3[(size_t)cn * H3 + gj];
        float t1r = tab1[(size_t)ci * H3 + 1024 + gj];
        float t2r = tab2[(size_t)fi * H3 + 1024 + gj];
        float t3r = tab3[(size_t)cn * H3 + 1024 + gj];
        float t1e = tab1[(size_t)ci * H3 + 2048 + gj];
        float t2e = tab2[(size_t)fi * H3 + 2048 + gj];
        float t3e = tab3[(size_t)cn * H3 + 2048 + gj];

        // ---- D(16x16) = A(16x1120) x B(1120x16): A global, B LDS ----
        vf4 acc0 = {0.f, 0.f, 0.f, 0.f}, acc1 = {0.f, 0.f, 0.f, 0.f};
#pragma unroll
        for (int kk = 0; kk < 32; kk += 2) {
            vbf8 a0 = *(const vbf8*)(Ah + kk * 512);
            vbf8 b0 = *(const vbf8*)(Bn + kk * 512);
            acc0 = __builtin_amdgcn_mfma_f32_16x16x32_bf16(a0, b0, acc0, 0, 0, 0);
            vbf8 a1 = *(const vbf8*)(Ah + (kk + 1) * 512);
            vbf8 b1 = *(const vbf8*)(Bn + (kk + 1) * 512);
            acc1 = __builtin_amdgcn_mfma_f32_16x16x32_bf16(a1, b1, acc1, 0, 0, 0);
        }
#pragma unroll
        for (int kq = 0; kq < 3; ++kq) {
            vbf8 a = *(const vbf8*)(Am + kq * 512);
            vbf8 b = *(const vbf8*)(Bn + (32 + kq) * 512);
            acc0 = __builtin_amdgcn_mfma_f32_16x16x32_bf16(a, b, acc0, 0, 0, 0);
        }
        vf4 acc = acc0 + acc1;

        // ---- exchange pre-activations (C: col=lane&15, row=(lane>>4)*4+r) ----
#pragma unroll
        for (int r = 0; r < 4; ++r)
            ex[m * 16 + ((lane >> 4) * 4 + r)][ng * 16 + (lane & 15)] = acc[r];
        __syncthreads();

        // ---- gates + state update ----
        int pp = gjl >> 3, jo = gjl & 7;
        float gu  = ex[gb][pp * 32 + jo]      + t1u + t2u + t3u;
        float gr  = ex[gb][pp * 32 + 8 + jo]  + t1r + t2r + t3r;
        float e1  = ex[gb][pp * 32 + 16 + jo];
        float ge2 = ex[gb][pp * 32 + 24 + jo] + t1e + t2e + t3e;
        float u  = 1.f / (1.f + expf(-gu));
        float r_ = 1.f / (1.f + expf(-gr));
        float e  = tanhf(r_ * e1 + ge2);
        hreg = u * hreg + (1.f - u) * e;

        // ---- coherent packed store of h (pair via shfl) ----
        __hip_bfloat16 hb = __float2bfloat16(hreg);
        int myv = (int)(*(unsigned short*)&hb);
        int nbv = __shfl_xor(myv, 1);
        if ((tid & 1) == 0) {
            unsigned int pk = ((unsigned)myv & 0xffffu) | ((unsigned)nbv << 16);
            __hip_atomic_store((unsigned int*)(Af + (size_t)(t + 1) * 32768 + wbase), pk,
                               __ATOMIC_RELAXED, __HIP_MEMORY_SCOPE_AGENT);
        }

        // ---- arrive: h-stores drained (syncthreads => vmcnt0), then RMW ----
        __syncthreads();
        if (tid == 0)
            __hip_atomic_fetch_add(&cnt[(wg & 7) * 64], 1u,
                                   __ATOMIC_RELEASE, __HIP_MEMORY_SCOPE_AGENT);

        if (t + 1 < LEN) {
            if (tid == 0) {
                unsigned tgt = (unsigned)(t + 1) * 8;   // 8 WGs per counter
                for (;;) {
                    unsigned c0 = __hip_atomic_load(&cnt[0],   __ATOMIC_RELAXED, __HIP_MEMORY_SCOPE_AGENT);
                    unsigned c1 = __hip_atomic_load(&cnt[64],  __ATOMIC_RELAXED, __HIP_MEMORY_SCOPE_AGENT);
                    unsigned c2 = __hip_atomic_load(&cnt[128], __ATOMIC_RELAXED, __HIP_MEMORY_SCOPE_AGENT);
                    unsigned c3 = __hip_atomic_load(&cnt[192], __ATOMIC_RELAXED, __HIP_MEMORY_SCOPE_AGENT);
                    unsigned c4 = __hip_atomic_load(&cnt[256], __ATOMIC_RELAXED, __HIP_MEMORY_SCOPE_AGENT);
                    unsigned c5 = __hip_atomic_load(&cnt[320], __ATOMIC_RELAXED, __HIP_MEMORY_SCOPE_AGENT);
                    unsigned c6 = __hip_atomic_load(&cnt[384], __ATOMIC_RELAXED, __HIP_MEMORY_SCOPE_AGENT);
                    unsigned c7 = __hip_atomic_load(&cnt[448], __ATOMIC_RELAXED, __HIP_MEMORY_SCOPE_AGENT);
                    if (c0 >= tgt && c1 >= tgt && c2 >= tgt && c3 >= tgt &&
                        c4 >= tgt && c5 >= tgt && c6 >= tgt && c7 >= tgt) break;
                    __builtin_amdgcn_s_sleep(1);
                }
                __builtin_amdgcn_fence(__ATOMIC_ACQUIRE, "agent");  // ONE inv/step (CU L1 + L2)
            }
            __syncthreads();
            asm volatile("" ::: "memory");   // no load hoisting above the barrier
        }
    }
}

// ============================ output MLPs (unchanged) ============================
#define LOADF4(arr, ptr) { float4 _v = *(const float4*)(ptr); arr[0]=_v.x; arr[1]=_v.y; arr[2]=_v.z; arr[3]=_v.w; }

__device__ __forceinline__ void load_y8(const unsigned short* __restrict__ Af,
                                        int tslot, int b, int kk, float* o) {
    size_t off = (size_t)tslot * 32768 +
                 (size_t)(((b >> 4) * 32 + (kk >> 5)) * 512) +
                 (size_t)(((b & 15) + 16 * ((kk >> 3) & 3)) * 8);
    vus8 v = *(const vus8*)(Af + off);
#pragma unroll
    for (int e = 0; e < 8; ++e) o[e] = __uint_as_float(((unsigned)v[e]) << 16);
}

__global__ __launch_bounds__(256) void out_mlp(const unsigned short* __restrict__ Af,
                                               const float* __restrict__ O1w, const float* __restrict__ O1b,
                                               const float* __restrict__ O2w, const float* __restrict__ O2b,
                                               const float* __restrict__ O3w, const float* __restrict__ O3b,
                                               const float* __restrict__ O4w, const float* __restrict__ O4b,
                                               float* __restrict__ out) {
    __shared__ float z[16][768];
    int tid = threadIdx.x;
    int ig = tid >> 6;
    int lane = tid & 63;
    int R0 = blockIdx.x * 16;

    int rb[4], rt[4];
#pragma unroll
    for (int i = 0; i < 4; ++i) {
        int R = R0 + ig * 4 + i;
        rb[i] = R >> 10;
        rt[i] = (R & 1023) + 1;
    }

    for (int pass = 0; pass < 3; ++pass) {
        int c = pass * 256 + lane * 4;
        float acc[4][4];
#pragma unroll
        for (int i = 0; i < 4; ++i)
#pragma unroll
            for (int jj = 0; jj < 4; ++jj) acc[i][jj] = O1b[c + jj];
        for (int kk = 0; kk < 768; kk += 8) {
            float w[8][4];
#pragma unroll
            for (int dk = 0; dk < 8; ++dk) LOADF4(w[dk], &O1w[(size_t)(kk + dk) * 768 + c]);
            float ya[4][8];
#pragma unroll
            for (int i = 0; i < 4; ++i) load_y8(Af, rt[i], rb[i], kk, ya[i]);
#pragma unroll
            for (int i = 0; i < 4; ++i)
#pragma unroll
                for (int dk = 0; dk < 8; ++dk)
#pragma unroll
                    for (int jj = 0; jj < 4; ++jj)
                        acc[i][jj] += ya[i][dk] * w[dk][jj];
        }
#pragma unroll
        for (int i = 0; i < 4; ++i)
#pragma unroll
            for (int jj = 0; jj < 4; ++jj)
                z[ig * 4 + i][c + jj] = fmaxf(acc[i][jj], 0.f);
    }
    __syncthreads();

    {
        int c = lane * 4;
        float acc[4][4];
#pragma unroll
        for (int i = 0; i < 4; ++i)
#pragma unroll
            for (int jj = 0; jj < 4; ++jj) acc[i][jj] = O2b[c + jj];
        for (int kk = 0; kk < 768; kk += 4) {
            float w[4][4];
#pragma unroll
            for (int dk = 0; dk < 4; ++dk) LOADF4(w[dk], &O2w[(size_t)(kk + dk) * 256 + c]);
            float za[4][4];
#pragma unroll
            for (int i = 0; i < 4; ++i) LOADF4(za[i], &z[ig * 4 + i][kk]);
#pragma unroll
            for (int i = 0; i < 4; ++i)
#pragma unroll
                for (int dk = 0; dk < 4; ++dk)
#pragma unroll
                    for (int jj = 0; jj < 4; ++jj)
                        acc[i][jj] += za[i][dk] * w[dk][jj];
        }
#pragma unroll
        for (int i = 0; i < 4; ++i) {
            int R = R0 + ig * 4 + i;
#pragma unroll
            for (int jj = 0; jj < 4; ++jj)
                out[(size_t)R * 256 + c + jj] = acc[i][jj];
        }
    }
    __syncthreads();

    {
        int c = lane * 4;
        float acc[4][4];
#pragma unroll
        for (int i = 0; i < 4; ++i)
#pragma unroll
            for (int jj = 0; jj < 4; ++jj) acc[i][jj] = O3b[c + jj];
        for (int kk = 0; kk < 256; kk += 8) {
            float w[8][4];
#pragma unroll
            for (int dk = 0; dk < 8; ++dk) LOADF4(w[dk], &O3w[(size_t)(kk + dk) * 256 + c]);
            float ya[4][8];
#pragma unroll
            for (int i = 0; i < 4; ++i) load_y8(Af, rt[i], rb[i], 768 + kk, ya[i]);
#pragma unroll
            for (int i = 0; i < 4; ++i)
#pragma unroll
                for (int dk = 0; dk < 8; ++dk)
#pragma unroll
                    for (int jj = 0; jj < 4; ++jj)
                        acc[i][jj] += ya[i][dk] * w[dk][jj];
        }
        __syncthreads();
#pragma unroll
        for (int i = 0; i < 4; ++i)
#pragma unroll
            for (int jj = 0; jj < 4; ++jj)
                z[ig * 4 + i][c + jj] = fmaxf(acc[i][jj], 0.f);
    }
    __syncthreads();

    {
        int c = lane * 4;
        float acc[4][4];
#pragma unroll
        for (int i = 0; i < 4; ++i)
#pragma unroll
            for (int jj = 0; jj < 4; ++jj) acc[i][jj] = O4b[c + jj];
        for (int kk = 0; kk < 256; kk += 4) {
            float w[4][4];
#pragma unroll
            for (int dk = 0; dk < 4; ++dk) LOADF4(w[dk], &O4w[(size_t)(kk + dk) * 256 + c]);
            float za[4][4];
#pragma unroll
            for (int i = 0; i < 4; ++i) LOADF4(za[i], &z[ig * 4 + i][kk]);
#pragma unroll
            for (int i = 0; i < 4; ++i)
#pragma unroll
                for (int dk = 0; dk < 4; ++dk)
#pragma unroll
                    for (int jj = 0; jj < 4; ++jj)
                        acc[i][jj] += za[i][dk] * w[dk][jj];
        }
#pragma unroll
        for (int i = 0; i < 4; ++i) {
            int R = R0 + ig * 4 + i;
#pragma unroll
            for (int jj = 0; jj < 4; ++jj)
                out[FOFS + (size_t)R * 256 + c + jj] = acc[i][jj];
        }
    }
}

// ============================ launch ============================
extern "C" void kernel_launch(void* const* d_in, const int* in_sizes, int n_in,
                              void* d_out, int out_size, void* d_ws, size_t ws_size,
                              hipStream_t stream) {
    const int*   x    = (const int*)d_in[0];
    const float* mel  = (const float*)d_in[1];
    const float* Rw   = (const float*)d_in[2];
    const float* Rb   = (const float*)d_in[3];
    const float* IW   = (const float*)d_in[4];
    const float* Ib   = (const float*)d_in[5];
    const float* O1w  = (const float*)d_in[6];
    const float* O1b  = (const float*)d_in[7];
    const float* O2w  = (const float*)d_in[8];
    const float* O2b  = (const float*)d_in[9];
    const float* O3w  = (const float*)d_in[10];
    const float* O3b  = (const float*)d_in[11];
    const float* O4w  = (const float*)d_in[12];
    const float* O4b  = (const float*)d_in[13];
    const float* cemb = (const float*)d_in[14];
    const float* femb = (const float*)d_in[15];
    char* wsb = (char*)d_ws;
    float* out = (float*)d_out;

    float* tab1 = (float*)(wsb + TAB1_B);
    float* tab2 = (float*)(wsb + TAB2_B);
    float* tab3 = (float*)(wsb + TAB3_B);
    unsigned short* Bf   = (unsigned short*)(wsb + BF_B);
    unsigned short* MelA = (unsigned short*)(wsb + MELA_B);
    unsigned short* Af   = (unsigned short*)(wsb + AF_B);
    unsigned int*   cnt  = (unsigned int*)(wsb + CNT_B);

    make_tables<<<9216, 256, 0, stream>>>(IW, Ib, cemb, femb, tab1, tab2, tab3);
    hipMemsetAsync((void*)Bf, 0, 4587520ull * 2, stream);       // pad/zero slots
    build_bfrag2<<<13440, 256, 0, stream>>>(Rw, IW, Rb, Bf);    // coalesced builder
    build_melA<<<12288, 256, 0, stream>>>(mel, MelA);
    hipMemsetAsync((void*)Af, 0, 65536, stream);   // h0 = 0
    hipMemsetAsync((void*)cnt, 0, 4096, stream);   // counters

    scan_persist<<<NWG, NTHR, 0, stream>>>(Bf, MelA, Af, tab1, tab2, tab3, x, cnt);

    out_mlp<<<2048, 256, 0, stream>>>(Af, O1w, O1b, O2w, O2b, O3w, O3b, O4w, O4b, out);
}

// Round 12
// 5065.019 us; speedup vs baseline: 1.4675x; 1.2323x over previous
//
#include <hip/hip_runtime.h>
#include <hip/hip_bf16.h>
#include <math.h>

typedef __attribute__((ext_vector_type(4))) float vf4;
typedef __attribute__((ext_vector_type(8))) short vbf8;
typedef __attribute__((ext_vector_type(8))) unsigned short vus8;

#define NWG   64
#define NTHR  512
#define LEN   1024
#define H3    3072
#define CND   80
#define EMBD  128

// ---- ws byte offsets ----
#define TAB1_B  0ull
#define TAB2_B  (TAB1_B + 786432ull*4)
#define TAB3_B  (TAB2_B + 786432ull*4)
#define BF_B    (TAB3_B + 786432ull*4)            // bfrag: 128oct*2which*35frag*512 bf16
#define MELA_B  (BF_B   + 4587520ull*2)           // melA : 1024t*2m*3frag*512 bf16
#define AF_B    (MELA_B + 3145728ull*2)           // Afrag: 1025t*64frag*512 bf16
#define CNT_B   (AF_B   + 33587200ull*2)          // 8 counters, 256B apart
#define W1F_B   (CNT_B + 4096ull)                 // O1w frags: 48nt*24kf*512 bf16
#define W2F_B   (W1F_B + 1179648ull)              // O2w frags: 16nt*24kf*512
#define W3F_B   (W2F_B + 393216ull)               // O3w frags: 16nt*8kf*512
#define W4F_B   (W3F_B + 131072ull)               // O4w frags: 16nt*8kf*512
#define FOFS    8388608ull                        // flogits offset in d_out

// ============================ prep kernels ============================

__global__ __launch_bounds__(256) void make_tables(const float* __restrict__ IW,
                                                   const float* __restrict__ Ib,
                                                   const float* __restrict__ cemb,
                                                   const float* __restrict__ femb,
                                                   float* __restrict__ tab1,
                                                   float* __restrict__ tab2,
                                                   float* __restrict__ tab3) {
    int blk = blockIdx.x;
    int table = blk / 3072;
    int rem = blk % 3072;
    int row = rem / 12;
    int cc = rem % 12;
    int col = cc * 256 + threadIdx.x;
    int ofs = CND + table * EMBD;
    const float* emb = (table == 1) ? femb : cemb;
    float acc = 0.f;
    for (int k = 0; k < EMBD; ++k)
        acc += emb[row * EMBD + k] * IW[(size_t)(ofs + k) * H3 + col];
    if (table == 0) acc += Ib[col];
    if (table == 2 && ((col & 1023) < 768)) acc = 0.f;
    float* dst = (table == 0) ? tab1 : (table == 1 ? tab2 : tab3);
    dst[(size_t)row * H3 + col] = acc;
}

// Coalesced B-frag builder for the scan weights (layout verified r11).
__global__ __launch_bounds__(256) void build_bfrag2(const float* __restrict__ Rw,
                                                    const float* __restrict__ IW,
                                                    const float* __restrict__ Rb,
                                                    unsigned short* __restrict__ Bf) {
    int idx = blockIdx.x * 256 + threadIdx.x;     // k*3072 + col, k in 0..1119
    int col = idx % 3072;
    int k   = idx / 3072;
    float v;
    if (k < 1024)       v = Rw[(size_t)k * H3 + col];
    else if (k < 1104)  v = IW[(size_t)(k - 1024) * H3 + col];
    else if (k == 1104) v = Rb[col];
    else return;                                   // pad rows stay zero

    int g  = col >> 10;          // 0:u 1:r 2:e
    int j  = col & 1023;
    int oct = j >> 3, jo = j & 7;
    int which, c;
    if (g < 2)      { which = 0; c = g * 8 + jo; }
    else {
        which = 1;
        if (k < 1024 || k == 1104) c = jo;         // e1: h-part + Rb
        else                        c = 8 + jo;    // e2: mel rows
    }
    int kk = k >> 5, r5 = k & 31;
    int lane = (r5 >> 3) * 16 + c;
    int elem = r5 & 7;
    size_t dst = (((size_t)oct * 2 + which) * 35 + kk) * 512 + lane * 8 + elem;
    __hip_bfloat16 hb = __float2bfloat16(v);
    Bf[dst] = *(unsigned short*)&hb;
}

__global__ __launch_bounds__(256) void build_melA(const float* __restrict__ mel,
                                                  unsigned short* __restrict__ MelA) {
    long idx = (long)blockIdx.x * 256 + threadIdx.x;
    int elem = idx & 7;
    int lane = (idx >> 3) & 63;
    int kkm  = (int)((idx >> 9) % 3);
    int m    = (int)((idx / 1536) & 1);
    int t    = (int)(idx / 3072);
    int b    = m * 16 + (lane & 15);
    int km   = kkm * 32 + ((lane >> 4) & 3) * 8 + elem;
    float v = (km < CND) ? mel[((size_t)b * LEN + t) * CND + km] : (km == CND ? 1.f : 0.f);
    __hip_bfloat16 hb = __float2bfloat16(v);
    MelA[idx] = *(unsigned short*)&hb;
}

// Generic weight->bf16 B-fragment converter: W is [K][N] row-major, K%32==0.
// Frag layout: [nt][kf][lane][elem]; lane = (col&15) + 16*((k&31)>>3), elem=k&7.
__global__ __launch_bounds__(256) void build_wfrag(const float* __restrict__ W,
                                                   unsigned short* __restrict__ Wf,
                                                   int K, int N) {
    int idx = blockIdx.x * 256 + threadIdx.x;
    if (idx >= K * N) return;
    int col = idx % N;
    int k   = idx / N;
    int nt = col >> 4, c = col & 15;
    int kf = k >> 5, k5 = k & 31;
    int lane = c + 16 * (k5 >> 3);
    int elem = k5 & 7;
    size_t dst = ((size_t)nt * (K >> 5) + kf) * 512 + (size_t)lane * 8 + elem;
    __hip_bfloat16 hb = __float2bfloat16(W[idx]);
    Wf[dst] = *(unsigned short*)&hb;
}

// ============================ persistent scan (r11 verbatim) ============================
__global__ __launch_bounds__(512, 2) void scan_persist(const unsigned short* __restrict__ Bf,
                                                       const unsigned short* __restrict__ MelA,
                                                       unsigned short* __restrict__ Af,
                                                       const float* __restrict__ tab1,
                                                       const float* __restrict__ tab2,
                                                       const float* __restrict__ tab3,
                                                       const int* __restrict__ xin,
                                                       unsigned int* __restrict__ cnt) {
    __shared__ __align__(16) unsigned short Bs[4 * 35 * 512];   // 143,360 B
    __shared__ float ex[32][68];                                //   8,704 B

    int tid = threadIdx.x;
    int wg  = blockIdx.x;
    int lane = tid & 63;
    int wv = tid >> 6;            // 0..7
    int m  = wv >> 2;             // A half (batch 0-15 / 16-31)
    int ng = wv & 3;              // B-set within WG

    {
        const unsigned int* src = (const unsigned int*)(Bf + (size_t)wg * 4 * 35 * 512);
        unsigned int* dst = (unsigned int*)Bs;
#pragma unroll
        for (int i = 0; i < 70; ++i) dst[tid + i * 512] = src[tid + i * 512];
    }
    __syncthreads();

    int gb = tid >> 4, gjl = tid & 15;
    int gj = wg * 16 + gjl;
    float hreg = 0.f;
    size_t wbase = (size_t)(((gb >> 4) * 32 + (gj >> 5)) * 512 +
                            ((gb & 15) + 16 * ((gj >> 3) & 3)) * 8 + (gj & 7));

    const unsigned short* Bn = Bs + (size_t)ng * 35 * 512 + lane * 8;

#pragma unroll 1
    for (int t = 0; t < LEN; ++t) {
        const unsigned short* Ah = Af + (size_t)t * 32768 + (size_t)(m * 32) * 512 + lane * 8;
        const unsigned short* Am = MelA + (size_t)t * 3072 + (size_t)(m * 3) * 512 + lane * 8;

        int ci = xin[(gb * LEN + t) * 2];
        int fi = xin[(gb * LEN + t) * 2 + 1];
        int cn = xin[(gb * LEN + ((t + 1) & (LEN - 1))) * 2];
        float t1u = tab1[(size_t)ci * H3 + gj];
        float t2u = tab2[(size_t)fi * H3 + gj];
        float t3u = tab3[(size_t)cn * H3 + gj];
        float t1r = tab1[(size_t)ci * H3 + 1024 + gj];
        float t2r = tab2[(size_t)fi * H3 + 1024 + gj];
        float t3r = tab3[(size_t)cn * H3 + 1024 + gj];
        float t1e = tab1[(size_t)ci * H3 + 2048 + gj];
        float t2e = tab2[(size_t)fi * H3 + 2048 + gj];
        float t3e = tab3[(size_t)cn * H3 + 2048 + gj];

        vf4 acc0 = {0.f, 0.f, 0.f, 0.f}, acc1 = {0.f, 0.f, 0.f, 0.f};
#pragma unroll
        for (int kk = 0; kk < 32; kk += 2) {
            vbf8 a0 = *(const vbf8*)(Ah + kk * 512);
            vbf8 b0 = *(const vbf8*)(Bn + kk * 512);
            acc0 = __builtin_amdgcn_mfma_f32_16x16x32_bf16(a0, b0, acc0, 0, 0, 0);
            vbf8 a1 = *(const vbf8*)(Ah + (kk + 1) * 512);
            vbf8 b1 = *(const vbf8*)(Bn + (kk + 1) * 512);
            acc1 = __builtin_amdgcn_mfma_f32_16x16x32_bf16(a1, b1, acc1, 0, 0, 0);
        }
#pragma unroll
        for (int kq = 0; kq < 3; ++kq) {
            vbf8 a = *(const vbf8*)(Am + kq * 512);
            vbf8 b = *(const vbf8*)(Bn + (32 + kq) * 512);
            acc0 = __builtin_amdgcn_mfma_f32_16x16x32_bf16(a, b, acc0, 0, 0, 0);
        }
        vf4 acc = acc0 + acc1;

#pragma unroll
        for (int r = 0; r < 4; ++r)
            ex[m * 16 + ((lane >> 4) * 4 + r)][ng * 16 + (lane & 15)] = acc[r];
        __syncthreads();

        int pp = gjl >> 3, jo = gjl & 7;
        float gu  = ex[gb][pp * 32 + jo]      + t1u + t2u + t3u;
        float gr  = ex[gb][pp * 32 + 8 + jo]  + t1r + t2r + t3r;
        float e1  = ex[gb][pp * 32 + 16 + jo];
        float ge2 = ex[gb][pp * 32 + 24 + jo] + t1e + t2e + t3e;
        float u  = 1.f / (1.f + expf(-gu));
        float r_ = 1.f / (1.f + expf(-gr));
        float e  = tanhf(r_ * e1 + ge2);
        hreg = u * hreg + (1.f - u) * e;

        __hip_bfloat16 hb = __float2bfloat16(hreg);
        int myv = (int)(*(unsigned short*)&hb);
        int nbv = __shfl_xor(myv, 1);
        if ((tid & 1) == 0) {
            unsigned int pk = ((unsigned)myv & 0xffffu) | ((unsigned)nbv << 16);
            __hip_atomic_store((unsigned int*)(Af + (size_t)(t + 1) * 32768 + wbase), pk,
                               __ATOMIC_RELAXED, __HIP_MEMORY_SCOPE_AGENT);
        }

        __syncthreads();
        if (tid == 0)
            __hip_atomic_fetch_add(&cnt[(wg & 7) * 64], 1u,
                                   __ATOMIC_RELEASE, __HIP_MEMORY_SCOPE_AGENT);

        if (t + 1 < LEN) {
            if (tid == 0) {
                unsigned tgt = (unsigned)(t + 1) * 8;   // 8 WGs per counter
                for (;;) {
                    unsigned c0 = __hip_atomic_load(&cnt[0],   __ATOMIC_RELAXED, __HIP_MEMORY_SCOPE_AGENT);
                    unsigned c1 = __hip_atomic_load(&cnt[64],  __ATOMIC_RELAXED, __HIP_MEMORY_SCOPE_AGENT);
                    unsigned c2 = __hip_atomic_load(&cnt[128], __ATOMIC_RELAXED, __HIP_MEMORY_SCOPE_AGENT);
                    unsigned c3 = __hip_atomic_load(&cnt[192], __ATOMIC_RELAXED, __HIP_MEMORY_SCOPE_AGENT);
                    unsigned c4 = __hip_atomic_load(&cnt[256], __ATOMIC_RELAXED, __HIP_MEMORY_SCOPE_AGENT);
                    unsigned c5 = __hip_atomic_load(&cnt[320], __ATOMIC_RELAXED, __HIP_MEMORY_SCOPE_AGENT);
                    unsigned c6 = __hip_atomic_load(&cnt[384], __ATOMIC_RELAXED, __HIP_MEMORY_SCOPE_AGENT);
                    unsigned c7 = __hip_atomic_load(&cnt[448], __ATOMIC_RELAXED, __HIP_MEMORY_SCOPE_AGENT);
                    if (c0 >= tgt && c1 >= tgt && c2 >= tgt && c3 >= tgt &&
                        c4 >= tgt && c5 >= tgt && c6 >= tgt && c7 >= tgt) break;
                    __builtin_amdgcn_s_sleep(1);
                }
                __builtin_amdgcn_fence(__ATOMIC_ACQUIRE, "agent");
            }
            __syncthreads();
            asm volatile("" ::: "memory");
        }
    }
}

// ============================ MFMA output MLPs ============================
// Block = one l-slot (32 rows = 32 batches at time l). 8 waves: m = wv>>2
// (row half), q = wv&3 (col group). Chain: GEMM1(relu)->Zc(LDS frags) ->
// GEMM2 -> clogits; GEMM3(relu)->Zf -> GEMM4 -> flogits. A-frags come from
// Af verbatim (already MFMA layout); weights pre-fragmented by build_wfrag.
__global__ __launch_bounds__(512) void out_mlp_mfma(
        const unsigned short* __restrict__ Af,
        const unsigned short* __restrict__ W1f, const float* __restrict__ O1b,
        const unsigned short* __restrict__ W2f, const float* __restrict__ O2b,
        const unsigned short* __restrict__ W3f, const float* __restrict__ O3b,
        const unsigned short* __restrict__ W4f, const float* __restrict__ O4b,
        float* __restrict__ out) {
    __shared__ __align__(16) unsigned short Zc[2 * 24 * 512];   // 48 KB
    __shared__ __align__(16) unsigned short Zf[2 * 8 * 512];    // 16 KB

    int tid = threadIdx.x;
    int lane = tid & 63;
    int wv = tid >> 6;
    int m = wv >> 2;
    int q = wv & 3;
    int l = blockIdx.x;
    int c16 = lane & 15;
    int rowq = lane >> 4;      // 0..3

    const unsigned short* Abase = Af + (size_t)(l + 1) * 32768 +
                                  (size_t)(m * 32) * 512 + (size_t)lane * 8;

    // ---- GEMM1: Zc = relu(Yc @ O1w + O1b); this wave: cols q*192..+191 ----
    {
        vf4 acc[12];
#pragma unroll
        for (int i = 0; i < 12; ++i) acc[i] = (vf4){0.f, 0.f, 0.f, 0.f};
        for (int kk = 0; kk < 24; ++kk) {
            vbf8 a = *(const vbf8*)(Abase + kk * 512);
#pragma unroll
            for (int i = 0; i < 12; ++i) {
                int nt = q * 12 + i;
                vbf8 b = *(const vbf8*)(W1f + ((size_t)nt * 24 + kk) * 512 + lane * 8);
                acc[i] = __builtin_amdgcn_mfma_f32_16x16x32_bf16(a, b, acc[i], 0, 0, 0);
            }
        }
#pragma unroll
        for (int i = 0; i < 12; ++i) {
            int nt = q * 12 + i;
            int col = nt * 16 + c16;
            float bias = O1b[col];
#pragma unroll
            for (int r = 0; r < 4; ++r) {
                float v = fmaxf(acc[i][r] + bias, 0.f);
                __hip_bfloat16 hb = __float2bfloat16(v);
                int my = (int)*(unsigned short*)&hb;
                int nb = __shfl_xor(my, 1);
                if ((lane & 1) == 0) {
                    unsigned pk = ((unsigned)my & 0xffffu) | ((unsigned)nb << 16);
                    int row = rowq * 4 + r;
                    int kk2 = col >> 5, k5 = col & 31;
                    int lp = row + 16 * (k5 >> 3);
                    int ep = k5 & 7;   // even
                    *(unsigned*)&Zc[(size_t)(m * 24 + kk2) * 512 + lp * 8 + ep] = pk;
                }
            }
        }
    }
    __syncthreads();

    // ---- GEMM2: clogits = Zc @ O2w + O2b; this wave: nt q*4..q*4+3 ----
    {
        vf4 acc[4];
#pragma unroll
        for (int i = 0; i < 4; ++i) acc[i] = (vf4){0.f, 0.f, 0.f, 0.f};
        for (int kk = 0; kk < 24; ++kk) {
            vbf8 a = *(const vbf8*)(Zc + (size_t)(m * 24 + kk) * 512 + lane * 8);
#pragma unroll
            for (int i = 0; i < 4; ++i) {
                int nt = q * 4 + i;
                vbf8 b = *(const vbf8*)(W2f + ((size_t)nt * 24 + kk) * 512 + lane * 8);
                acc[i] = __builtin_amdgcn_mfma_f32_16x16x32_bf16(a, b, acc[i], 0, 0, 0);
            }
        }
#pragma unroll
        for (int i = 0; i < 4; ++i) {
            int nt = q * 4 + i;
            int col = nt * 16 + c16;
            float bias = O2b[col];
#pragma unroll
            for (int r = 0; r < 4; ++r) {
                int n = m * 16 + rowq * 4 + r;
                out[((size_t)n * 1024 + l) * 256 + col] = acc[i][r] + bias;
            }
        }
    }

    // ---- GEMM3: Zf = relu(Yf @ O3w + O3b); A-frags 24..31 of Af ----
    {
        vf4 acc[4];
#pragma unroll
        for (int i = 0; i < 4; ++i) acc[i] = (vf4){0.f, 0.f, 0.f, 0.f};
        for (int kf = 0; kf < 8; ++kf) {
            vbf8 a = *(const vbf8*)(Abase + (24 + kf) * 512);
#pragma unroll
            for (int i = 0; i < 4; ++i) {
                int nt = q * 4 + i;
                vbf8 b = *(const vbf8*)(W3f + ((size_t)nt * 8 + kf) * 512 + lane * 8);
                acc[i] = __builtin_amdgcn_mfma_f32_16x16x32_bf16(a, b, acc[i], 0, 0, 0);
            }
        }
#pragma unroll
        for (int i = 0; i < 4; ++i) {
            int nt = q * 4 + i;
            int col = nt * 16 + c16;
            float bias = O3b[col];
#pragma unroll
            for (int r = 0; r < 4; ++r) {
                float v = fmaxf(acc[i][r] + bias, 0.f);
                __hip_bfloat16 hb = __float2bfloat16(v);
                int my = (int)*(unsigned short*)&hb;
                int nb = __shfl_xor(my, 1);
                if ((lane & 1) == 0) {
                    unsigned pk = ((unsigned)my & 0xffffu) | ((unsigned)nb << 16);
                    int row = rowq * 4 + r;
                    int kk2 = col >> 5, k5 = col & 31;
                    int lp = row + 16 * (k5 >> 3);
                    int ep = k5 & 7;
                    *(unsigned*)&Zf[(size_t)(m * 8 + kk2) * 512 + lp * 8 + ep] = pk;
                }
            }
        }
    }
    __syncthreads();

    // ---- GEMM4: flogits = Zf @ O4w + O4b ----
    {
        vf4 acc[4];
#pragma unroll
        for (int i = 0; i < 4; ++i) acc[i] = (vf4){0.f, 0.f, 0.f, 0.f};
        for (int kf = 0; kf < 8; ++kf) {
            vbf8 a = *(const vbf8*)(Zf + (size_t)(m * 8 + kf) * 512 + lane * 8);
#pragma unroll
            for (int i = 0; i < 4; ++i) {
                int nt = q * 4 + i;
                vbf8 b = *(const vbf8*)(W4f + ((size_t)nt * 8 + kf) * 512 + lane * 8);
                acc[i] = __builtin_amdgcn_mfma_f32_16x16x32_bf16(a, b, acc[i], 0, 0, 0);
            }
        }
#pragma unroll
        for (int i = 0; i < 4; ++i) {
            int nt = q * 4 + i;
            int col = nt * 16 + c16;
            float bias = O4b[col];
#pragma unroll
            for (int r = 0; r < 4; ++r) {
                int n = m * 16 + rowq * 4 + r;
                out[FOFS + ((size_t)n * 1024 + l) * 256 + col] = acc[i][r] + bias;
            }
        }
    }
}

// ============================ launch ============================
extern "C" void kernel_launch(void* const* d_in, const int* in_sizes, int n_in,
                              void* d_out, int out_size, void* d_ws, size_t ws_size,
                              hipStream_t stream) {
    const int*   x    = (const int*)d_in[0];
    const float* mel  = (const float*)d_in[1];
    const float* Rw   = (const float*)d_in[2];
    const float* Rb   = (const float*)d_in[3];
    const float* IW   = (const float*)d_in[4];
    const float* Ib   = (const float*)d_in[5];
    const float* O1w  = (const float*)d_in[6];
    const float* O1b  = (const float*)d_in[7];
    const float* O2w  = (const float*)d_in[8];
    const float* O2b  = (const float*)d_in[9];
    const float* O3w  = (const float*)d_in[10];
    const float* O3b  = (const float*)d_in[11];
    const float* O4w  = (const float*)d_in[12];
    const float* O4b  = (const float*)d_in[13];
    const float* cemb = (const float*)d_in[14];
    const float* femb = (const float*)d_in[15];
    char* wsb = (char*)d_ws;
    float* out = (float*)d_out;

    float* tab1 = (float*)(wsb + TAB1_B);
    float* tab2 = (float*)(wsb + TAB2_B);
    float* tab3 = (float*)(wsb + TAB3_B);
    unsigned short* Bf   = (unsigned short*)(wsb + BF_B);
    unsigned short* MelA = (unsigned short*)(wsb + MELA_B);
    unsigned short* Af   = (unsigned short*)(wsb + AF_B);
    unsigned int*   cnt  = (unsigned int*)(wsb + CNT_B);
    unsigned short* W1f  = (unsigned short*)(wsb + W1F_B);
    unsigned short* W2f  = (unsigned short*)(wsb + W2F_B);
    unsigned short* W3f  = (unsigned short*)(wsb + W3F_B);
    unsigned short* W4f  = (unsigned short*)(wsb + W4F_B);

    make_tables<<<9216, 256, 0, stream>>>(IW, Ib, cemb, femb, tab1, tab2, tab3);
    hipMemsetAsync((void*)Bf, 0, 4587520ull * 2, stream);
    build_bfrag2<<<13440, 256, 0, stream>>>(Rw, IW, Rb, Bf);
    build_melA<<<12288, 256, 0, stream>>>(mel, MelA);
    build_wfrag<<<2304, 256, 0, stream>>>(O1w, W1f, 768, 768);
    build_wfrag<<<768,  256, 0, stream>>>(O2w, W2f, 768, 256);
    build_wfrag<<<256,  256, 0, stream>>>(O3w, W3f, 256, 256);
    build_wfrag<<<256,  256, 0, stream>>>(O4w, W4f, 256, 256);
    hipMemsetAsync((void*)Af, 0, 65536, stream);   // h0 = 0
    hipMemsetAsync((void*)cnt, 0, 4096, stream);   // counters

    scan_persist<<<NWG, NTHR, 0, stream>>>(Bf, MelA, Af, tab1, tab2, tab3, x, cnt);

    out_mlp_mfma<<<1024, 512, 0, stream>>>(Af, W1f, O1b, W2f, O2b, W3f, O3b, W4f, O4b, out);
}

// Round 13
// 4138.188 us; speedup vs baseline: 1.7961x; 1.2240x over previous
//
#include <hip/hip_runtime.h>
#include <hip/hip_bf16.h>
#include <math.h>

typedef __attribute__((ext_vector_type(4))) float vf4;
typedef __attribute__((ext_vector_type(8))) short vbf8;
typedef __attribute__((ext_vector_type(8))) unsigned short vus8;

#define NWG   128
#define NTHR  256
#define LEN   1024
#define H3    3072
#define CND   80
#define EMBD  128

// ---- ws byte offsets ----
#define TAB1_B  0ull
#define TAB2_B  (TAB1_B + 786432ull*4)
#define TAB3_B  (TAB2_B + 786432ull*4)
#define BF_B    (TAB3_B + 786432ull*4)            // bfrag: 128oct*2which*35frag*512 bf16
#define MELA_B  (BF_B   + 4587520ull*2)           // melA : 1024t*2m*3frag*512 bf16
#define AF_B    (MELA_B + 3145728ull*2)           // Afrag: 1025t*64frag*512 bf16
#define CNT_B   (AF_B   + 33587200ull*2)          // (unused now)
#define W1F_B   (CNT_B + 4096ull)                 // O1w frags
#define W2F_B   (W1F_B + 1179648ull)
#define W3F_B   (W2F_B + 393216ull)
#define W4F_B   (W3F_B + 131072ull)
#define FOFS    8388608ull                        // flogits offset in d_out

// ============================ prep kernels ============================

__global__ __launch_bounds__(256) void make_tables(const float* __restrict__ IW,
                                                   const float* __restrict__ Ib,
                                                   const float* __restrict__ cemb,
                                                   const float* __restrict__ femb,
                                                   float* __restrict__ tab1,
                                                   float* __restrict__ tab2,
                                                   float* __restrict__ tab3) {
    int blk = blockIdx.x;
    int table = blk / 3072;
    int rem = blk % 3072;
    int row = rem / 12;
    int cc = rem % 12;
    int col = cc * 256 + threadIdx.x;
    int ofs = CND + table * EMBD;
    const float* emb = (table == 1) ? femb : cemb;
    float acc = 0.f;
    for (int k = 0; k < EMBD; ++k)
        acc += emb[row * EMBD + k] * IW[(size_t)(ofs + k) * H3 + col];
    if (table == 0) acc += Ib[col];
    if (table == 2 && ((col & 1023) < 768)) acc = 0.f;
    float* dst = (table == 0) ? tab1 : (table == 1 ? tab2 : tab3);
    dst[(size_t)row * H3 + col] = acc;
}

__global__ __launch_bounds__(256) void build_bfrag2(const float* __restrict__ Rw,
                                                    const float* __restrict__ IW,
                                                    const float* __restrict__ Rb,
                                                    unsigned short* __restrict__ Bf) {
    int idx = blockIdx.x * 256 + threadIdx.x;     // k*3072 + col, k in 0..1119
    int col = idx % 3072;
    int k   = idx / 3072;
    float v;
    if (k < 1024)       v = Rw[(size_t)k * H3 + col];
    else if (k < 1104)  v = IW[(size_t)(k - 1024) * H3 + col];
    else if (k == 1104) v = Rb[col];
    else return;

    int g  = col >> 10;
    int j  = col & 1023;
    int oct = j >> 3, jo = j & 7;
    int which, c;
    if (g < 2)      { which = 0; c = g * 8 + jo; }
    else {
        which = 1;
        if (k < 1024 || k == 1104) c = jo;
        else                        c = 8 + jo;
    }
    int kk = k >> 5, r5 = k & 31;
    int lane = (r5 >> 3) * 16 + c;
    int elem = r5 & 7;
    size_t dst = (((size_t)oct * 2 + which) * 35 + kk) * 512 + lane * 8 + elem;
    __hip_bfloat16 hb = __float2bfloat16(v);
    Bf[dst] = *(unsigned short*)&hb;
}

__global__ __launch_bounds__(256) void build_melA(const float* __restrict__ mel,
                                                  unsigned short* __restrict__ MelA) {
    long idx = (long)blockIdx.x * 256 + threadIdx.x;
    int elem = idx & 7;
    int lane = (idx >> 3) & 63;
    int kkm  = (int)((idx >> 9) % 3);
    int m    = (int)((idx / 1536) & 1);
    int t    = (int)(idx / 3072);
    int b    = m * 16 + (lane & 15);
    int km   = kkm * 32 + ((lane >> 4) & 3) * 8 + elem;
    float v = (km < CND) ? mel[((size_t)b * LEN + t) * CND + km] : (km == CND ? 1.f : 0.f);
    __hip_bfloat16 hb = __float2bfloat16(v);
    MelA[idx] = *(unsigned short*)&hb;
}

__global__ __launch_bounds__(256) void build_wfrag(const float* __restrict__ W,
                                                   unsigned short* __restrict__ Wf,
                                                   int K, int N) {
    int idx = blockIdx.x * 256 + threadIdx.x;
    if (idx >= K * N) return;
    int col = idx % N;
    int k   = idx / N;
    int nt = col >> 4, c = col & 15;
    int kf = k >> 5, k5 = k & 31;
    int lane = c + 16 * (k5 >> 3);
    int elem = k5 & 7;
    size_t dst = ((size_t)nt * (K >> 5) + kf) * 512 + (size_t)lane * 8 + elem;
    __hip_bfloat16 hb = __float2bfloat16(W[idx]);
    Wf[dst] = *(unsigned short*)&hb;
}

// ============================ persistent scan: barrier-free sentinel dataflow ============================
// 128 WGs x 256 thr (4 waves: m=wv>>1, n=wv&1). NO global barrier, NO fence:
//  - Af pre-seeded to 0xFF (packed bf16 -NaN sentinel; finite gate math can
//    never produce 0xFFFFFFFF in a packed u32). Producers fire relaxed agent-
//    atomic u32 stores and move on.
//  - Each wave atomic-pulls its 16-frag slice of Af[t] (always-fresh, r6/r7-
//    verified load path), retrying any u64 whose half is still sentinel, and
//    stages it in LDS hstage. Dedup: 64KB/WG/step, no duplication.
//  - Tables / Bf / MelA / xin: plain cached loads, NEVER invalidated -> hot.
//  - Two LDS-local __syncthreads per step; zero device-scope sync ops.
__device__ __forceinline__ int is_sent(unsigned long long q) {
    return ((unsigned)q == 0xFFFFFFFFu) || ((unsigned)(q >> 32) == 0xFFFFFFFFu);
}

__global__ __launch_bounds__(256, 1) void scan_persist(const unsigned short* __restrict__ Bf,
                                                       const unsigned short* __restrict__ MelA,
                                                       unsigned short* __restrict__ Af,
                                                       const float* __restrict__ tab1,
                                                       const float* __restrict__ tab2,
                                                       const float* __restrict__ tab3,
                                                       const int* __restrict__ xin) {
    __shared__ __align__(16) unsigned short Bs[2 * 35 * 512];     // 71,680 B
    __shared__ __align__(16) unsigned short hstage[64 * 512];     // 65,536 B
    __shared__ float ex[32][36];                                  //  4,608 B

    int tid = threadIdx.x;
    int wg  = blockIdx.x;
    int lane = tid & 63;
    int wv = tid >> 6;            // 0..3
    int m  = wv >> 1;             // A half (batch 0-15 / 16-31)
    int n  = wv & 1;              // 0: [u|r] cols, 1: [e1|e2] cols

    // ---- stage this WG's B fragments into LDS (one-time) ----
    {
        const unsigned int* src = (const unsigned int*)(Bf + (size_t)wg * (2 * 35 * 512));
        unsigned int* dst = (unsigned int*)Bs;
#pragma unroll
        for (int i = 0; i < 70; ++i) dst[tid + i * 256] = src[tid + i * 256];
    }
    __syncthreads();

    // gate role: one (b, j) per thread
    int gb = tid >> 3, gjl = tid & 7;
    int gj = wg * 8 + gjl;
    float hreg = 0.f;
    size_t wbase = (size_t)(((gb >> 4) * 32 + (gj >> 5)) * 512 +
                            ((gb & 15) + 16 * ((gj >> 3) & 3)) * 8 + (gj & 7));

    const unsigned short* Bn = Bs + (n * 35) * 512 + lane * 8;

#pragma unroll 1
    for (int t = 0; t < LEN; ++t) {
        // ---- table gathers (cached, hot; issued early, consumed late) ----
        int ci = xin[(gb * LEN + t) * 2];
        int fi = xin[(gb * LEN + t) * 2 + 1];
        int cn = xin[(gb * LEN + ((t + 1) & (LEN - 1))) * 2];
        float t1u = tab1[(size_t)ci * H3 + gj];
        float t2u = tab2[(size_t)fi * H3 + gj];
        float t3u = tab3[(size_t)cn * H3 + gj];
        float t1r = tab1[(size_t)ci * H3 + 1024 + gj];
        float t2r = tab2[(size_t)fi * H3 + 1024 + gj];
        float t3r = tab3[(size_t)cn * H3 + 1024 + gj];
        float t1e = tab1[(size_t)ci * H3 + 2048 + gj];
        float t2e = tab2[(size_t)fi * H3 + 2048 + gj];
        float t3e = tab3[(size_t)cn * H3 + 2048 + gj];

        // ---- pull this wave's 16-frag slice of Af[t] into hstage ----
#pragma unroll
        for (int bat = 0; bat < 2; ++bat) {
            int f0 = wv * 16 + bat * 8;
            const unsigned long long* bp =
                (const unsigned long long*)(Af + (size_t)t * 32768 + (size_t)f0 * 512) + lane * 2;
            unsigned long long q[16];
#pragma unroll
            for (int i = 0; i < 8; ++i) {
                q[2 * i]     = __hip_atomic_load(bp + i * 128,     __ATOMIC_RELAXED, __HIP_MEMORY_SCOPE_AGENT);
                q[2 * i + 1] = __hip_atomic_load(bp + i * 128 + 1, __ATOMIC_RELAXED, __HIP_MEMORY_SCOPE_AGENT);
            }
            for (;;) {
                int bad = 0;
#pragma unroll
                for (int i = 0; i < 16; ++i) bad |= is_sent(q[i]);
                if (!__any(bad)) break;
                __builtin_amdgcn_s_sleep(1);
#pragma unroll
                for (int i = 0; i < 8; ++i) {
                    q[2 * i]     = __hip_atomic_load(bp + i * 128,     __ATOMIC_RELAXED, __HIP_MEMORY_SCOPE_AGENT);
                    q[2 * i + 1] = __hip_atomic_load(bp + i * 128 + 1, __ATOMIC_RELAXED, __HIP_MEMORY_SCOPE_AGENT);
                }
            }
#pragma unroll
            for (int i = 0; i < 8; ++i) {
                union { unsigned long long qq[2]; vus8 v; } u;
                u.qq[0] = q[2 * i]; u.qq[1] = q[2 * i + 1];
                *(vus8*)(hstage + (size_t)(f0 + i) * 512 + lane * 8) = u.v;
            }
        }
        __syncthreads();   // hstage complete

        // ---- D(16x16) = A(16x1120) x B(1120x16): A,B from LDS ----
        const unsigned short* Ah = hstage + (size_t)(m * 32) * 512 + lane * 8;
        const unsigned short* Am = MelA + (size_t)t * 3072 + (size_t)(m * 3) * 512 + lane * 8;
        vf4 acc0 = {0.f, 0.f, 0.f, 0.f}, acc1 = {0.f, 0.f, 0.f, 0.f};
#pragma unroll
        for (int kk = 0; kk < 32; kk += 2) {
            vbf8 a0 = *(const vbf8*)(Ah + kk * 512);
            vbf8 b0 = *(const vbf8*)(Bn + kk * 512);
            acc0 = __builtin_amdgcn_mfma_f32_16x16x32_bf16(a0, b0, acc0, 0, 0, 0);
            vbf8 a1 = *(const vbf8*)(Ah + (kk + 1) * 512);
            vbf8 b1 = *(const vbf8*)(Bn + (kk + 1) * 512);
            acc1 = __builtin_amdgcn_mfma_f32_16x16x32_bf16(a1, b1, acc1, 0, 0, 0);
        }
#pragma unroll
        for (int kq = 0; kq < 3; ++kq) {
            vbf8 a = *(const vbf8*)(Am + kq * 512);
            vbf8 b = *(const vbf8*)(Bn + (32 + kq) * 512);
            acc0 = __builtin_amdgcn_mfma_f32_16x16x32_bf16(a, b, acc0, 0, 0, 0);
        }
        vf4 acc = acc0 + acc1;

        // ---- exchange pre-activations (C: col=lane&15, row=(lane>>4)*4+r) ----
#pragma unroll
        for (int r = 0; r < 4; ++r)
            ex[m * 16 + ((lane >> 4) * 4 + r)][n * 16 + (lane & 15)] = acc[r];
        __syncthreads();

        // ---- gates + state update ----
        float gu  = ex[gb][gjl]      + t1u + t2u + t3u;
        float gr  = ex[gb][8 + gjl]  + t1r + t2r + t3r;
        float e1  = ex[gb][16 + gjl];
        float ge2 = ex[gb][24 + gjl] + t1e + t2e + t3e;
        float u  = 1.f / (1.f + expf(-gu));
        float r_ = 1.f / (1.f + expf(-gr));
        float e  = tanhf(r_ * e1 + ge2);
        hreg = u * hreg + (1.f - u) * e;

        // ---- fire-and-forget packed h store (pair via shfl) ----
        __hip_bfloat16 hb = __float2bfloat16(hreg);
        int myv = (int)(*(unsigned short*)&hb);
        int nbv = __shfl_xor(myv, 1);
        if ((tid & 1) == 0) {
            unsigned int pk = ((unsigned)myv & 0xffffu) | ((unsigned)nbv << 16);
            __hip_atomic_store((unsigned int*)(Af + (size_t)(t + 1) * 32768 + wbase), pk,
                               __ATOMIC_RELAXED, __HIP_MEMORY_SCOPE_AGENT);
        }
        // no drain, no arrival, no fence -- consumers sentinel-poll the data.
    }
}

// ============================ MFMA output MLPs (r12 verbatim) ============================
__global__ __launch_bounds__(512) void out_mlp_mfma(
        const unsigned short* __restrict__ Af,
        const unsigned short* __restrict__ W1f, const float* __restrict__ O1b,
        const unsigned short* __restrict__ W2f, const float* __restrict__ O2b,
        const unsigned short* __restrict__ W3f, const float* __restrict__ O3b,
        const unsigned short* __restrict__ W4f, const float* __restrict__ O4b,
        float* __restrict__ out) {
    __shared__ __align__(16) unsigned short Zc[2 * 24 * 512];   // 48 KB
    __shared__ __align__(16) unsigned short Zf[2 * 8 * 512];    // 16 KB

    int tid = threadIdx.x;
    int lane = tid & 63;
    int wv = tid >> 6;
    int m = wv >> 2;
    int q = wv & 3;
    int l = blockIdx.x;
    int c16 = lane & 15;
    int rowq = lane >> 4;

    const unsigned short* Abase = Af + (size_t)(l + 1) * 32768 +
                                  (size_t)(m * 32) * 512 + (size_t)lane * 8;

    {
        vf4 acc[12];
#pragma unroll
        for (int i = 0; i < 12; ++i) acc[i] = (vf4){0.f, 0.f, 0.f, 0.f};
        for (int kk = 0; kk < 24; ++kk) {
            vbf8 a = *(const vbf8*)(Abase + kk * 512);
#pragma unroll
            for (int i = 0; i < 12; ++i) {
                int nt = q * 12 + i;
                vbf8 b = *(const vbf8*)(W1f + ((size_t)nt * 24 + kk) * 512 + lane * 8);
                acc[i] = __builtin_amdgcn_mfma_f32_16x16x32_bf16(a, b, acc[i], 0, 0, 0);
            }
        }
#pragma unroll
        for (int i = 0; i < 12; ++i) {
            int nt = q * 12 + i;
            int col = nt * 16 + c16;
            float bias = O1b[col];
#pragma unroll
            for (int r = 0; r < 4; ++r) {
                float v = fmaxf(acc[i][r] + bias, 0.f);
                __hip_bfloat16 hb = __float2bfloat16(v);
                int my = (int)*(unsigned short*)&hb;
                int nb = __shfl_xor(my, 1);
                if ((lane & 1) == 0) {
                    unsigned pk = ((unsigned)my & 0xffffu) | ((unsigned)nb << 16);
                    int row = rowq * 4 + r;
                    int kk2 = col >> 5, k5 = col & 31;
                    int lp = row + 16 * (k5 >> 3);
                    int ep = k5 & 7;
                    *(unsigned*)&Zc[(size_t)(m * 24 + kk2) * 512 + lp * 8 + ep] = pk;
                }
            }
        }
    }
    __syncthreads();

    {
        vf4 acc[4];
#pragma unroll
        for (int i = 0; i < 4; ++i) acc[i] = (vf4){0.f, 0.f, 0.f, 0.f};
        for (int kk = 0; kk < 24; ++kk) {
            vbf8 a = *(const vbf8*)(Zc + (size_t)(m * 24 + kk) * 512 + lane * 8);
#pragma unroll
            for (int i = 0; i < 4; ++i) {
                int nt = q * 4 + i;
                vbf8 b = *(const vbf8*)(W2f + ((size_t)nt * 24 + kk) * 512 + lane * 8);
                acc[i] = __builtin_amdgcn_mfma_f32_16x16x32_bf16(a, b, acc[i], 0, 0, 0);
            }
        }
#pragma unroll
        for (int i = 0; i < 4; ++i) {
            int nt = q * 4 + i;
            int col = nt * 16 + c16;
            float bias = O2b[col];
#pragma unroll
            for (int r = 0; r < 4; ++r) {
                int n = m * 16 + rowq * 4 + r;
                out[((size_t)n * 1024 + l) * 256 + col] = acc[i][r] + bias;
            }
        }
    }

    {
        vf4 acc[4];
#pragma unroll
        for (int i = 0; i < 4; ++i) acc[i] = (vf4){0.f, 0.f, 0.f, 0.f};
        for (int kf = 0; kf < 8; ++kf) {
            vbf8 a = *(const vbf8*)(Abase + (24 + kf) * 512);
#pragma unroll
            for (int i = 0; i < 4; ++i) {
                int nt = q * 4 + i;
                vbf8 b = *(const vbf8*)(W3f + ((size_t)nt * 8 + kf) * 512 + lane * 8);
                acc[i] = __builtin_amdgcn_mfma_f32_16x16x32_bf16(a, b, acc[i], 0, 0, 0);
            }
        }
#pragma unroll
        for (int i = 0; i < 4; ++i) {
            int nt = q * 4 + i;
            int col = nt * 16 + c16;
            float bias = O3b[col];
#pragma unroll
            for (int r = 0; r < 4; ++r) {
                float v = fmaxf(acc[i][r] + bias, 0.f);
                __hip_bfloat16 hb = __float2bfloat16(v);
                int my = (int)*(unsigned short*)&hb;
                int nb = __shfl_xor(my, 1);
                if ((lane & 1) == 0) {
                    unsigned pk = ((unsigned)my & 0xffffu) | ((unsigned)nb << 16);
                    int row = rowq * 4 + r;
                    int kk2 = col >> 5, k5 = col & 31;
                    int lp = row + 16 * (k5 >> 3);
                    int ep = k5 & 7;
                    *(unsigned*)&Zf[(size_t)(m * 8 + kk2) * 512 + lp * 8 + ep] = pk;
                }
            }
        }
    }
    __syncthreads();

    {
        vf4 acc[4];
#pragma unroll
        for (int i = 0; i < 4; ++i) acc[i] = (vf4){0.f, 0.f, 0.f, 0.f};
        for (int kf = 0; kf < 8; ++kf) {
            vbf8 a = *(const vbf8*)(Zf + (size_t)(m * 8 + kf) * 512 + lane * 8);
#pragma unroll
            for (int i = 0; i < 4; ++i) {
                int nt = q * 4 + i;
                vbf8 b = *(const vbf8*)(W4f + ((size_t)nt * 8 + kf) * 512 + lane * 8);
                acc[i] = __builtin_amdgcn_mfma_f32_16x16x32_bf16(a, b, acc[i], 0, 0, 0);
            }
        }
#pragma unroll
        for (int i = 0; i < 4; ++i) {
            int nt = q * 4 + i;
            int col = nt * 16 + c16;
            float bias = O4b[col];
#pragma unroll
            for (int r = 0; r < 4; ++r) {
                int n = m * 16 + rowq * 4 + r;
                out[FOFS + ((size_t)n * 1024 + l) * 256 + col] = acc[i][r] + bias;
            }
        }
    }
}

// ============================ launch ============================
extern "C" void kernel_launch(void* const* d_in, const int* in_sizes, int n_in,
                              void* d_out, int out_size, void* d_ws, size_t ws_size,
                              hipStream_t stream) {
    const int*   x    = (const int*)d_in[0];
    const float* mel  = (const float*)d_in[1];
    const float* Rw   = (const float*)d_in[2];
    const float* Rb   = (const float*)d_in[3];
    const float* IW   = (const float*)d_in[4];
    const float* Ib   = (const float*)d_in[5];
    const float* O1w  = (const float*)d_in[6];
    const float* O1b  = (const float*)d_in[7];
    const float* O2w  = (const float*)d_in[8];
    const float* O2b  = (const float*)d_in[9];
    const float* O3w  = (const float*)d_in[10];
    const float* O3b  = (const float*)d_in[11];
    const float* O4w  = (const float*)d_in[12];
    const float* O4b  = (const float*)d_in[13];
    const float* cemb = (const float*)d_in[14];
    const float* femb = (const float*)d_in[15];
    char* wsb = (char*)d_ws;
    float* out = (float*)d_out;

    float* tab1 = (float*)(wsb + TAB1_B);
    float* tab2 = (float*)(wsb + TAB2_B);
    float* tab3 = (float*)(wsb + TAB3_B);
    unsigned short* Bf   = (unsigned short*)(wsb + BF_B);
    unsigned short* MelA = (unsigned short*)(wsb + MELA_B);
    unsigned short* Af   = (unsigned short*)(wsb + AF_B);
    unsigned short* W1f  = (unsigned short*)(wsb + W1F_B);
    unsigned short* W2f  = (unsigned short*)(wsb + W2F_B);
    unsigned short* W3f  = (unsigned short*)(wsb + W3F_B);
    unsigned short* W4f  = (unsigned short*)(wsb + W4F_B);

    make_tables<<<9216, 256, 0, stream>>>(IW, Ib, cemb, femb, tab1, tab2, tab3);
    hipMemsetAsync((void*)Bf, 0, 4587520ull * 2, stream);
    build_bfrag2<<<13440, 256, 0, stream>>>(Rw, IW, Rb, Bf);
    build_melA<<<12288, 256, 0, stream>>>(mel, MelA);
    build_wfrag<<<2304, 256, 0, stream>>>(O1w, W1f, 768, 768);
    build_wfrag<<<768,  256, 0, stream>>>(O2w, W2f, 768, 256);
    build_wfrag<<<256,  256, 0, stream>>>(O3w, W3f, 256, 256);
    build_wfrag<<<256,  256, 0, stream>>>(O4w, W4f, 256, 256);
    hipMemsetAsync((void*)Af, 0xFF, 33587200ull * 2, stream);   // sentinel-seed all slots
    hipMemsetAsync((void*)Af, 0, 65536, stream);                // h0 = 0 (slot 0 readable)

    scan_persist<<<NWG, NTHR, 0, stream>>>(Bf, MelA, Af, tab1, tab2, tab3, x);

    out_mlp_mfma<<<1024, 512, 0, stream>>>(Af, W1f, O1b, W2f, O2b, W3f, O3b, W4f, O4b, out);
}